// Round 2
// baseline (555.960 us; speedup 1.0000x reference)
//
#include <hip/hip_runtime.h>

// Problem constants (from reference)
#define BB      4096
#define EE      128
#define MM      8
#define NSTEPS  3
#define HH      256
#define CC      16

#define TS      16                    // samples per block
#define NBMAX   (BB/TS + MM)          // 264: worst-case padded blocks per step
#define XROW    (EE + 4)              // 132: LDS row stride for x/bias
#define HROW    (2*EE + 4)            // 260: LDS row stride for h

// ---------------------------------------------------------------------------
// prep: ballot-based counting sort of samples into module buckets per step.
// 1 block x 1024 threads (16 waves), zero atomics, no div/mod in hot loops.
// ---------------------------------------------------------------------------
__global__ __launch_bounds__(1024) void prep_kernel(
    const int* __restrict__ module_ids,   // (B, NSTEPS)
    int* __restrict__ blockMod,           // (NSTEPS, NBMAX)   module per block, -1 = unused
    int* __restrict__ perm)               // (NSTEPS, NBMAX*TS) sample ids, -1 = pad
{
    __shared__ int waveCnt [16][NSTEPS][MM];
    __shared__ int waveBase[16][NSTEPS][MM];
    __shared__ int cursor  [16][NSTEPS][MM];
    __shared__ int base        [NSTEPS][MM];
    const int tid  = threadIdx.x;
    const int wid  = tid >> 6;
    const int lane = tid & 63;

    if (tid < 16*NSTEPS*MM) (&waveCnt[0][0][0])[tid] = 0;
    for (int i = tid; i < NSTEPS*NBMAX*TS; i += 1024) perm[i] = -1;
    __syncthreads();

    // phase 1: per-wave histograms (each wave owns 256 samples)
    for (int t = 0; t < NSTEPS; t++) {
        #pragma unroll
        for (int c = 0; c < 4; c++) {
            const int s = (wid << 8) + (c << 6) + lane;
            const int m = module_ids[s*NSTEPS + t];
            unsigned long long bal[MM];
            #pragma unroll
            for (int k = 0; k < MM; k++) bal[k] = __ballot(m == k);
            if (lane < MM) waveCnt[wid][t][lane] += __popcll(bal[lane]);
        }
    }
    __syncthreads();

    // phase 2: tiny serial plan per step (3 threads)
    if (tid < NSTEPS) {
        const int t = tid;
        int blk = 0;
        for (int m = 0; m < MM; m++) {
            int tot = 0;
            for (int w = 0; w < 16; w++) { waveBase[w][t][m] = tot; tot += waveCnt[w][t][m]; }
            base[t][m] = blk * TS;
            const int nb = (tot + TS - 1) / TS;
            for (int b = 0; b < nb; b++) blockMod[t*NBMAX + blk + b] = m;
            blk += nb;
        }
        for (; blk < NBMAX; blk++) blockMod[t*NBMAX + blk] = -1;
    }
    __syncthreads();

    if (tid < 16*NSTEPS*MM) {
        const int w = tid / (NSTEPS*MM), r = tid % (NSTEPS*MM), t = r / MM, m = r % MM;
        cursor[w][t][m] = base[t][m] + waveBase[w][t][m];
    }
    __syncthreads();

    // phase 3: scatter with in-wave ranking (same chunk order as phase 1)
    for (int t = 0; t < NSTEPS; t++) {
        #pragma unroll
        for (int c = 0; c < 4; c++) {
            const int s = (wid << 8) + (c << 6) + lane;
            const int m = module_ids[s*NSTEPS + t];
            unsigned long long bal[MM];
            #pragma unroll
            for (int k = 0; k < MM; k++) bal[k] = __ballot(m == k);
            const unsigned long long below = (1ull << lane) - 1ull;
            const int rank = __popcll(bal[m] & below);
            const int pos  = cursor[wid][t][m] + rank;
            perm[t*NBMAX*TS + pos] = s;
            if (lane < MM) cursor[wid][t][lane] += __popcll(bal[lane]);
        }
    }
}

// ---------------------------------------------------------------------------
// one recurrent step for a 16-sample, module-uniform block.
// 512 threads (8 waves -> 2 waves/SIMD), tile = 1 sample x 4 output cols.
// ---------------------------------------------------------------------------
__global__ __launch_bounds__(512) void step_kernel(
    const int t,
    const int*   __restrict__ entity_ids,  // (B, NSTEPS+1)
    const float* __restrict__ embedding,   // (N_ENT, E)
    const float* __restrict__ W_in,  const float* __restrict__ b_in,
    const float* __restrict__ W_bias, const float* __restrict__ b_bias,
    const float* __restrict__ W_f,   const float* __restrict__ b_f,
    const int*   __restrict__ blockMod,
    const int*   __restrict__ perm,
    float* __restrict__ xbuf)              // (B, E) state, updated in place
{
    const int bid = blockIdx.x;
    const int m = blockMod[t*NBMAX + bid];
    if (m < 0) return;                      // padded/unused block (uniform)
    const int tid = threadIdx.x;

    // xs+bs (2*16*132 floats = 4224) reused as hs (16*260 = 4160) after sync
    __shared__ __align__(16) float smem[2*TS*XROW];
    __shared__ int sid[TS];
    float (*xs)[XROW] = (float (*)[XROW])smem;
    float (*bs)[XROW] = (float (*)[XROW])(smem + TS*XROW);
    float (*hs)[HROW] = (float (*)[HROW])smem;

    if (tid < TS) sid[tid] = perm[(t*NBMAX + bid)*TS + tid];
    __syncthreads();

    // gather x (from embedding at t==0, else xbuf) and bias rows: 1 float4/thread
    {
        const int r = tid >> 5, q = tid & 31;
        const int s = sid[r];
        float4 xv = make_float4(0.f,0.f,0.f,0.f);
        float4 bv = xv;
        if (s >= 0) {
            if (t == 0) {
                const int e0 = entity_ids[s*(NSTEPS+1)];
                xv = *(const float4*)(embedding + (size_t)e0*EE + q*4);
            } else {
                xv = *(const float4*)(xbuf + (size_t)s*EE + q*4);
            }
            const int e1 = entity_ids[s*(NSTEPS+1) + t + 1];
            bv = *(const float4*)(embedding + (size_t)e1*EE + q*4);
        }
        *(float4*)(&xs[r][q*4]) = xv;
        *(float4*)(&bs[r][q*4]) = bv;
    }
    __syncthreads();

    const int og = tid & 31, sg = tid >> 5;   // 32 col-groups x 16 samples
    const int o0 = og * 4;

    // h_in = relu(x @ W_in[m] + b_in[m]); h_bi = relu(bias @ W_bias[m] + b_bias[m])
    float acc1[4] = {0.f,0.f,0.f,0.f};
    float acc2[4] = {0.f,0.f,0.f,0.f};
    {
        const float* __restrict__ Wi = W_in   + (size_t)m*EE*EE + o0;
        const float* __restrict__ Wb = W_bias + (size_t)m*EE*EE + o0;
        #pragma unroll 2
        for (int e4 = 0; e4 < EE; e4 += 4) {
            const float4 xv = *(const float4*)(&xs[sg][e4]);   // ds_read_b128 broadcast
            const float4 bv = *(const float4*)(&bs[sg][e4]);
            const float xa[4] = {xv.x, xv.y, xv.z, xv.w};
            const float ba[4] = {bv.x, bv.y, bv.z, bv.w};
            #pragma unroll
            for (int u = 0; u < 4; u++) {
                const float4 w1 = *(const float4*)(Wi + (size_t)(e4+u)*EE);
                const float4 w2 = *(const float4*)(Wb + (size_t)(e4+u)*EE);
                acc1[0] = fmaf(xa[u], w1.x, acc1[0]);
                acc1[1] = fmaf(xa[u], w1.y, acc1[1]);
                acc1[2] = fmaf(xa[u], w1.z, acc1[2]);
                acc1[3] = fmaf(xa[u], w1.w, acc1[3]);
                acc2[0] = fmaf(ba[u], w2.x, acc2[0]);
                acc2[1] = fmaf(ba[u], w2.y, acc2[1]);
                acc2[2] = fmaf(ba[u], w2.z, acc2[2]);
                acc2[3] = fmaf(ba[u], w2.w, acc2[3]);
            }
        }
    }
    __syncthreads();   // all xs/bs reads done; hs aliases that memory
    {
        const float4 bi = *(const float4*)(b_in   + m*EE + o0);
        const float4 bb = *(const float4*)(b_bias + m*EE + o0);
        float4 h1, h2;
        h1.x = fmaxf(acc1[0] + bi.x, 0.f);
        h1.y = fmaxf(acc1[1] + bi.y, 0.f);
        h1.z = fmaxf(acc1[2] + bi.z, 0.f);
        h1.w = fmaxf(acc1[3] + bi.w, 0.f);
        h2.x = fmaxf(acc2[0] + bb.x, 0.f);
        h2.y = fmaxf(acc2[1] + bb.y, 0.f);
        h2.z = fmaxf(acc2[2] + bb.z, 0.f);
        h2.w = fmaxf(acc2[3] + bb.w, 0.f);
        *(float4*)(&hs[sg][o0])      = h1;
        *(float4*)(&hs[sg][EE + o0]) = h2;
    }
    __syncthreads();

    // x_new = tanh(h @ W_f[m] + b_f[m])
    float acc3[4] = {0.f,0.f,0.f,0.f};
    {
        const float* __restrict__ Wf = W_f + (size_t)m*2*EE*EE + o0;
        #pragma unroll 2
        for (int f4 = 0; f4 < 2*EE; f4 += 4) {
            const float4 hv = *(const float4*)(&hs[sg][f4]);
            const float ha[4] = {hv.x, hv.y, hv.z, hv.w};
            #pragma unroll
            for (int u = 0; u < 4; u++) {
                const float4 w = *(const float4*)(Wf + (size_t)(f4+u)*EE);
                acc3[0] = fmaf(ha[u], w.x, acc3[0]);
                acc3[1] = fmaf(ha[u], w.y, acc3[1]);
                acc3[2] = fmaf(ha[u], w.z, acc3[2]);
                acc3[3] = fmaf(ha[u], w.w, acc3[3]);
            }
        }
    }
    {
        const int s = sid[sg];
        if (s >= 0) {
            const float4 bf = *(const float4*)(b_f + m*EE + o0);
            float4 xn;
            xn.x = tanhf(acc3[0] + bf.x);
            xn.y = tanhf(acc3[1] + bf.y);
            xn.z = tanhf(acc3[2] + bf.z);
            xn.w = tanhf(acc3[3] + bf.w);
            *(float4*)(xbuf + (size_t)s*EE + o0) = xn;
        }
    }
}

// ---------------------------------------------------------------------------
// head: out = relu(x @ W1 + b1) @ W2 + b2.  256 blocks x 512 threads, 16 samples/blk
// ---------------------------------------------------------------------------
__global__ __launch_bounds__(512) void final_kernel(
    const float* __restrict__ xbuf,
    const float* __restrict__ W1, const float* __restrict__ b1,
    const float* __restrict__ W2, const float* __restrict__ b2,
    float* __restrict__ out)
{
    const int tid = threadIdx.x, bid = blockIdx.x;
    const int sbase = bid * TS;
    __shared__ __align__(16) float smem[TS*(HH+4)];   // hs (16x260); xs aliases front
    float (*xs)[XROW]   = (float (*)[XROW])smem;
    float (*hs)[HH+4]   = (float (*)[HH+4])smem;

    {   // gather x: 1 float4/thread
        const int r = tid >> 5, q = tid & 31;
        *(float4*)(&xs[r][q*4]) = *(const float4*)(xbuf + (size_t)(sbase + r)*EE + q*4);
    }
    __syncthreads();

    const int og = tid & 31, sg = tid >> 5;   // 32 col-groups(x8) x 16 samples
    const int o0 = og * 8;
    float acc[8] = {0.f,0.f,0.f,0.f,0.f,0.f,0.f,0.f};
    #pragma unroll 2
    for (int e4 = 0; e4 < EE; e4 += 4) {
        const float4 xv = *(const float4*)(&xs[sg][e4]);
        const float xa[4] = {xv.x, xv.y, xv.z, xv.w};
        #pragma unroll
        for (int u = 0; u < 4; u++) {
            const float4 wa = *(const float4*)(W1 + (size_t)(e4+u)*HH + o0);
            const float4 wb = *(const float4*)(W1 + (size_t)(e4+u)*HH + o0 + 4);
            acc[0] = fmaf(xa[u], wa.x, acc[0]);
            acc[1] = fmaf(xa[u], wa.y, acc[1]);
            acc[2] = fmaf(xa[u], wa.z, acc[2]);
            acc[3] = fmaf(xa[u], wa.w, acc[3]);
            acc[4] = fmaf(xa[u], wb.x, acc[4]);
            acc[5] = fmaf(xa[u], wb.y, acc[5]);
            acc[6] = fmaf(xa[u], wb.z, acc[6]);
            acc[7] = fmaf(xa[u], wb.w, acc[7]);
        }
    }
    __syncthreads();   // xs reads done; hs aliases
    {
        const float4 ba = *(const float4*)(b1 + o0);
        const float4 bb = *(const float4*)(b1 + o0 + 4);
        float4 h1, h2;
        h1.x = fmaxf(acc[0] + ba.x, 0.f);
        h1.y = fmaxf(acc[1] + ba.y, 0.f);
        h1.z = fmaxf(acc[2] + ba.z, 0.f);
        h1.w = fmaxf(acc[3] + ba.w, 0.f);
        h2.x = fmaxf(acc[4] + bb.x, 0.f);
        h2.y = fmaxf(acc[5] + bb.y, 0.f);
        h2.z = fmaxf(acc[6] + bb.z, 0.f);
        h2.w = fmaxf(acc[7] + bb.w, 0.f);
        *(float4*)(&hs[sg][o0])     = h1;
        *(float4*)(&hs[sg][o0 + 4]) = h2;
    }
    __syncthreads();
    if (tid < TS*CC) {
        const int s = tid >> 4;          // 16 samples
        const int c = tid & 15;          // 16 cols
        float a = 0.f;
        #pragma unroll 4
        for (int f = 0; f < HH; f++) a = fmaf(hs[s][f], W2[f*CC + c], a);
        out[(size_t)(sbase + s)*CC + c] = a + b2[c];
    }
}

// ---------------------------------------------------------------------------
extern "C" void kernel_launch(void* const* d_in, const int* in_sizes, int n_in,
                              void* d_out, int out_size, void* d_ws, size_t ws_size,
                              hipStream_t stream) {
    const int*   entity_ids = (const int*)  d_in[0];
    const int*   module_ids = (const int*)  d_in[1];
    const float* embedding  = (const float*)d_in[2];
    const float* W_in   = (const float*)d_in[3];
    const float* b_in   = (const float*)d_in[4];
    const float* W_bias = (const float*)d_in[5];
    const float* b_bias = (const float*)d_in[6];
    const float* W_f    = (const float*)d_in[7];
    const float* b_f    = (const float*)d_in[8];
    const float* W1     = (const float*)d_in[9];
    const float* b1     = (const float*)d_in[10];
    const float* W2     = (const float*)d_in[11];
    const float* b2     = (const float*)d_in[12];
    float* out = (float*)d_out;

    // workspace: blockMod (1024 ints, 792 used) | perm (3*264*16 = 12672 ints) | xbuf (B*E floats)
    int* blockMod = (int*)d_ws;
    int* perm     = blockMod + 1024;
    float* xbuf   = (float*)(blockMod + 1024 + NSTEPS*NBMAX*TS);  // byte off 54784, 16B aligned

    prep_kernel<<<1, 1024, 0, stream>>>(module_ids, blockMod, perm);
    for (int t = 0; t < NSTEPS; t++) {
        step_kernel<<<NBMAX, 512, 0, stream>>>(t, entity_ids, embedding,
                                               W_in, b_in, W_bias, b_bias, W_f, b_f,
                                               blockMod, perm, xbuf);
    }
    final_kernel<<<BB/TS, 512, 0, stream>>>(xbuf, W1, b1, W2, b2, out);
}

// Round 3
// 376.951 us; speedup vs baseline: 1.4749x; 1.4749x over previous
//
#include <hip/hip_runtime.h>

// Problem constants (from reference)
#define BB      4096
#define EE      128
#define MM      8
#define NSTEPS  3
#define HH      256
#define CC      16

#define TS      16                    // samples per block (MFMA M-tile)
#define NBMAX   (BB/TS + MM)          // 264: worst-case padded blocks per step
#define HT      17                    // transposed h LDS stride (2-way bank alias = free)
#define FB      1024                  // ushorts per weight frag-block (512 hi + 512 lo)

// frag-block index ranges in converted weight buffer wf:
//   W_in  : (m*8+nt)*4+kc            -> [0,256)
//   W_bias: 256 + (m*8+nt)*4+kc      -> [256,512)
//   W_f   : 512 + (m*8+nt)*8+kc      -> [512,1024)
//   W1    : 1024 + nt*4+kc (nt<16)   -> [1024,1088)
//   W2    : 1088 + kc      (kc<8)    -> [1088,1096)
#define NFRAGBLK 1096

typedef __attribute__((ext_vector_type(8))) short  bf16x8;
typedef __attribute__((ext_vector_type(4))) float  f32x4;

__device__ __forceinline__ unsigned short bf16_rn(float v) {
    unsigned u = __float_as_uint(v);
    return (unsigned short)((u + 0x7FFFu + ((u >> 16) & 1u)) >> 16);
}
__device__ __forceinline__ float bf16_f(unsigned short h) {
    return __uint_as_float(((unsigned)h) << 16);
}
// split 8 fp32 into hi/lo bf16 fragments
__device__ __forceinline__ void split8(const float* v, bf16x8& hi, bf16x8& lo) {
    #pragma unroll
    for (int i = 0; i < 8; i++) {
        unsigned short h = bf16_rn(v[i]);
        hi[i] = (short)h;
        lo[i] = (short)bf16_rn(v[i] - bf16_f(h));
    }
}
#define MFMA(a,b,c) __builtin_amdgcn_mfma_f32_16x16x32_bf16((a),(b),(c),0,0,0)
// split-precision accumulate: (ah+al)*(bh+bl) ~= ah*bh + ah*bl + al*bh
__device__ __forceinline__ f32x4 mfma3(bf16x8 ah, bf16x8 al, bf16x8 bh, bf16x8 bl, f32x4 c) {
    c = MFMA(ah, bh, c);
    c = MFMA(ah, bl, c);
    c = MFMA(al, bh, c);
    return c;
}

// ---------------------------------------------------------------------------
// convert: fp32 weights -> split-bf16 B-fragment-linear layout.
// One block per frag-block; element el=(lane,j): B[k=kc*32+(lane>>4)*8+j][n=nt*16+(lane&15)]
// ---------------------------------------------------------------------------
__global__ __launch_bounds__(256) void convert_kernel(
    const float* __restrict__ W_in, const float* __restrict__ W_bias,
    const float* __restrict__ W_f,  const float* __restrict__ W1,
    const float* __restrict__ W2,   unsigned short* __restrict__ wf)
{
    const int b = blockIdx.x, tid = threadIdx.x;
    unsigned short* dhi = wf + (size_t)b * FB;
    unsigned short* dlo = dhi + 512;
    #pragma unroll
    for (int half = 0; half < 2; half++) {
        const int el = tid + half * 256;
        const int ln = el >> 3, j = el & 7;
        const int krel = ((ln >> 4) << 3) + j;   // 0..31
        const int nrel = ln & 15;
        float v;
        if (b < 512) {
            const int bb = b & 255;
            const int kc = bb & 3, nt = (bb >> 2) & 7, m = bb >> 5;
            const float* src = (b < 256 ? W_in : W_bias) + (size_t)m * EE * EE;
            v = src[(size_t)(kc*32 + krel) * EE + nt*16 + nrel];
        } else if (b < 1024) {
            const int bb = b - 512;
            const int kc = bb & 7, nt = (bb >> 3) & 7, m = bb >> 6;
            v = W_f[(size_t)m * 2*EE*EE + (size_t)(kc*32 + krel) * EE + nt*16 + nrel];
        } else if (b < 1088) {
            const int bb = b - 1024;
            const int kc = bb & 3, nt = bb >> 2;
            v = W1[(size_t)(kc*32 + krel) * HH + nt*16 + nrel];
        } else {
            const int kc = b - 1088;
            v = W2[(size_t)(kc*32 + krel) * CC + nrel];
        }
        const unsigned short h = bf16_rn(v);
        dhi[el] = h;
        dlo[el] = bf16_rn(v - bf16_f(h));
    }
}

// ---------------------------------------------------------------------------
// prep: ballot-based counting sort of samples into module buckets per step.
// ---------------------------------------------------------------------------
__global__ __launch_bounds__(1024) void prep_kernel(
    const int* __restrict__ module_ids,
    int* __restrict__ blockMod,           // (NSTEPS, NBMAX)
    int* __restrict__ perm)               // (NSTEPS, NBMAX*TS), -1 = pad
{
    __shared__ int waveCnt [16][NSTEPS][MM];
    __shared__ int waveBase[16][NSTEPS][MM];
    __shared__ int cursor  [16][NSTEPS][MM];
    __shared__ int base        [NSTEPS][MM];
    const int tid  = threadIdx.x;
    const int wid  = tid >> 6;
    const int lane = tid & 63;

    if (tid < 16*NSTEPS*MM) (&waveCnt[0][0][0])[tid] = 0;
    for (int i = tid; i < NSTEPS*NBMAX*TS; i += 1024) perm[i] = -1;
    __syncthreads();

    for (int t = 0; t < NSTEPS; t++) {
        #pragma unroll
        for (int c = 0; c < 4; c++) {
            const int s = (wid << 8) + (c << 6) + lane;
            const int m = module_ids[s*NSTEPS + t];
            unsigned long long bal[MM];
            #pragma unroll
            for (int k = 0; k < MM; k++) bal[k] = __ballot(m == k);
            if (lane < MM) waveCnt[wid][t][lane] += __popcll(bal[lane]);
        }
    }
    __syncthreads();

    if (tid < NSTEPS) {
        const int t = tid;
        int blk = 0;
        for (int m = 0; m < MM; m++) {
            int tot = 0;
            for (int w = 0; w < 16; w++) { waveBase[w][t][m] = tot; tot += waveCnt[w][t][m]; }
            base[t][m] = blk * TS;
            const int nb = (tot + TS - 1) / TS;
            for (int b = 0; b < nb; b++) blockMod[t*NBMAX + blk + b] = m;
            blk += nb;
        }
        for (; blk < NBMAX; blk++) blockMod[t*NBMAX + blk] = -1;
    }
    __syncthreads();

    if (tid < 16*NSTEPS*MM) {
        const int w = tid / (NSTEPS*MM), r = tid % (NSTEPS*MM), t = r / MM, m = r % MM;
        cursor[w][t][m] = base[t][m] + waveBase[w][t][m];
    }
    __syncthreads();

    for (int t = 0; t < NSTEPS; t++) {
        #pragma unroll
        for (int c = 0; c < 4; c++) {
            const int s = (wid << 8) + (c << 6) + lane;
            const int m = module_ids[s*NSTEPS + t];
            unsigned long long bal[MM];
            #pragma unroll
            for (int k = 0; k < MM; k++) bal[k] = __ballot(m == k);
            const unsigned long long below = (1ull << lane) - 1ull;
            const int rank = __popcll(bal[m] & below);
            perm[t*NBMAX*TS + cursor[wid][t][m] + rank] = s;
            if (lane < MM) cursor[wid][t][lane] += __popcll(bal[lane]);
        }
    }
}

// ---------------------------------------------------------------------------
// step: one recurrent step for a 16-sample module-uniform block, split-bf16 MFMA.
// 256 threads = 4 waves; wave w owns output n-tiles {w, w+4}.
// ---------------------------------------------------------------------------
__global__ __launch_bounds__(256) void step_kernel(
    const int t,
    const int*   __restrict__ entity_ids,
    const float* __restrict__ embedding,
    const float* __restrict__ b_in, const float* __restrict__ b_bias,
    const float* __restrict__ b_f,
    const unsigned short* __restrict__ wf,
    const int*   __restrict__ blockMod,
    const int*   __restrict__ perm,
    float* __restrict__ xbuf)
{
    const int bid = blockIdx.x;
    const int m = blockMod[t*NBMAX + bid];
    if (m < 0) return;
    const int tid  = threadIdx.x;
    const int lane = tid & 63, wave = tid >> 6;
    const int row16 = lane & 15, quad = lane >> 4;
    const int pb = (t*NBMAX + bid)*TS;

    __shared__ float hs[2*EE][HT];    // transposed: hs[col][sample]

    // sample ids: A-row sample and store-row samples
    const int sA = perm[pb + row16];
    int sSt[4];
    #pragma unroll
    for (int r = 0; r < 4; r++) sSt[r] = perm[pb + quad*4 + r];
    const int sAc = sA < 0 ? 0 : sA;

    const float* xrow;
    if (t == 0) {
        const int e0 = entity_ids[sAc*(NSTEPS+1)];
        xrow = embedding + (size_t)e0*EE;
    } else {
        xrow = xbuf + (size_t)sAc*EE;
    }
    const int e1 = entity_ids[sAc*(NSTEPS+1) + t + 1];
    const float* brow = embedding + (size_t)e1*EE;

    // A-fragments for x and entity-bias, all 4 K-chunks
    bf16x8 xh[4], xl[4], eh[4], el_[4];
    #pragma unroll
    for (int kc = 0; kc < 4; kc++) {
        const int off = kc*32 + quad*8;
        float vv[8];
        *(float4*)(vv)     = *(const float4*)(xrow + off);
        *(float4*)(vv + 4) = *(const float4*)(xrow + off + 4);
        split8(vv, xh[kc], xl[kc]);
        *(float4*)(vv)     = *(const float4*)(brow + off);
        *(float4*)(vv + 4) = *(const float4*)(brow + off + 4);
        split8(vv, eh[kc], el_[kc]);
    }

    // h_in = relu(x W_in + b_in), h_bi = relu(bias W_bias + b_bias)
    f32x4 aci[2] = {{0.f,0.f,0.f,0.f},{0.f,0.f,0.f,0.f}};
    f32x4 acb[2] = {{0.f,0.f,0.f,0.f},{0.f,0.f,0.f,0.f}};
    #pragma unroll
    for (int i = 0; i < 2; i++) {
        const int nt = wave + 4*i;
        #pragma unroll
        for (int kc = 0; kc < 4; kc++) {
            const unsigned short* bI = wf + (size_t)((m*8 + nt)*4 + kc)*FB;
            const unsigned short* bB = wf + (size_t)(256 + (m*8 + nt)*4 + kc)*FB;
            const bf16x8 wih = *(const bf16x8*)(bI + lane*8);
            const bf16x8 wil = *(const bf16x8*)(bI + 512 + lane*8);
            const bf16x8 wbh = *(const bf16x8*)(bB + lane*8);
            const bf16x8 wbl = *(const bf16x8*)(bB + 512 + lane*8);
            aci[i] = mfma3(xh[kc], xl[kc], wih, wil, aci[i]);
            acb[i] = mfma3(eh[kc], el_[kc], wbh, wbl, acb[i]);
        }
    }

    // epilogue 1: relu + bias, write h transposed to LDS
    #pragma unroll
    for (int i = 0; i < 2; i++) {
        const int col = (wave + 4*i)*16 + row16;
        const float bin = b_in [m*EE + col];
        const float bbi = b_bias[m*EE + col];
        #pragma unroll
        for (int r = 0; r < 4; r++) {
            hs[col][quad*4 + r]      = fmaxf(aci[i][r] + bin, 0.f);
            hs[EE + col][quad*4 + r] = fmaxf(acb[i][r] + bbi, 0.f);
        }
    }
    __syncthreads();

    // x_new = tanh(h W_f + b_f), K = 256
    f32x4 acf[2] = {{0.f,0.f,0.f,0.f},{0.f,0.f,0.f,0.f}};
    #pragma unroll
    for (int kc = 0; kc < 8; kc++) {
        float vv[8];
        #pragma unroll
        for (int j = 0; j < 8; j++) vv[j] = hs[kc*32 + quad*8 + j][row16];
        bf16x8 ah, al;
        split8(vv, ah, al);
        #pragma unroll
        for (int i = 0; i < 2; i++) {
            const int nt = wave + 4*i;
            const unsigned short* bF = wf + (size_t)(512 + (m*8 + nt)*8 + kc)*FB;
            const bf16x8 wfh = *(const bf16x8*)(bF + lane*8);
            const bf16x8 wfl = *(const bf16x8*)(bF + 512 + lane*8);
            acf[i] = mfma3(ah, al, wfh, wfl, acf[i]);
        }
    }
    #pragma unroll
    for (int i = 0; i < 2; i++) {
        const int col = (wave + 4*i)*16 + row16;
        const float bfv = b_f[m*EE + col];
        #pragma unroll
        for (int r = 0; r < 4; r++) {
            const int s = sSt[r];
            if (s >= 0) xbuf[(size_t)s*EE + col] = tanhf(acf[i][r] + bfv);
        }
    }
}

// ---------------------------------------------------------------------------
// head: out = relu(x W1 + b1) W2 + b2.  256 blocks x 256 threads, 16 samples/blk.
// W1: wave owns n-tiles {w,w+4,w+8,w+12}; W2: K-split across waves + LDS reduce.
// ---------------------------------------------------------------------------
__global__ __launch_bounds__(256) void final_kernel(
    const float* __restrict__ xbuf,
    const float* __restrict__ b1v, const float* __restrict__ b2,
    const unsigned short* __restrict__ wf,
    float* __restrict__ out)
{
    const int tid = threadIdx.x, bid = blockIdx.x;
    const int lane = tid & 63, wave = tid >> 6;
    const int row16 = lane & 15, quad = lane >> 4;
    const int sbase = bid * TS;

    __shared__ float hs[HH][HT];
    __shared__ float red[4][TS][CC];

    const float* xrow = xbuf + (size_t)(sbase + row16)*EE;
    bf16x8 xh[4], xl[4];
    #pragma unroll
    for (int kc = 0; kc < 4; kc++) {
        const int off = kc*32 + quad*8;
        float vv[8];
        *(float4*)(vv)     = *(const float4*)(xrow + off);
        *(float4*)(vv + 4) = *(const float4*)(xrow + off + 4);
        split8(vv, xh[kc], xl[kc]);
    }

    f32x4 a1[4] = {{0.f,0.f,0.f,0.f},{0.f,0.f,0.f,0.f},{0.f,0.f,0.f,0.f},{0.f,0.f,0.f,0.f}};
    #pragma unroll
    for (int i = 0; i < 4; i++) {
        const int nt = wave + 4*i;
        #pragma unroll
        for (int kc = 0; kc < 4; kc++) {
            const unsigned short* bW = wf + (size_t)(1024 + nt*4 + kc)*FB;
            const bf16x8 wh = *(const bf16x8*)(bW + lane*8);
            const bf16x8 wl = *(const bf16x8*)(bW + 512 + lane*8);
            a1[i] = mfma3(xh[kc], xl[kc], wh, wl, a1[i]);
        }
    }
    #pragma unroll
    for (int i = 0; i < 4; i++) {
        const int col = (wave + 4*i)*16 + row16;
        const float b = b1v[col];
        #pragma unroll
        for (int r = 0; r < 4; r++)
            hs[col][quad*4 + r] = fmaxf(a1[i][r] + b, 0.f);
    }
    __syncthreads();

    f32x4 a2 = {0.f,0.f,0.f,0.f};
    #pragma unroll
    for (int u = 0; u < 2; u++) {
        const int kc = wave*2 + u;
        float vv[8];
        #pragma unroll
        for (int j = 0; j < 8; j++) vv[j] = hs[kc*32 + quad*8 + j][row16];
        bf16x8 ah, al;
        split8(vv, ah, al);
        const unsigned short* bW = wf + (size_t)(1088 + kc)*FB;
        const bf16x8 wh = *(const bf16x8*)(bW + lane*8);
        const bf16x8 wl = *(const bf16x8*)(bW + 512 + lane*8);
        a2 = mfma3(ah, al, wh, wl, a2);
    }
    #pragma unroll
    for (int r = 0; r < 4; r++) red[wave][quad*4 + r][row16] = a2[r];
    __syncthreads();

    {
        const int s = tid >> 4, c = tid & 15;
        const float v = red[0][s][c] + red[1][s][c] + red[2][s][c] + red[3][s][c] + b2[c];
        out[(size_t)(sbase + s)*CC + c] = v;
    }
}

// ---------------------------------------------------------------------------
extern "C" void kernel_launch(void* const* d_in, const int* in_sizes, int n_in,
                              void* d_out, int out_size, void* d_ws, size_t ws_size,
                              hipStream_t stream) {
    const int*   entity_ids = (const int*)  d_in[0];
    const int*   module_ids = (const int*)  d_in[1];
    const float* embedding  = (const float*)d_in[2];
    const float* W_in   = (const float*)d_in[3];
    const float* b_in   = (const float*)d_in[4];
    const float* W_bias = (const float*)d_in[5];
    const float* b_bias = (const float*)d_in[6];
    const float* W_f    = (const float*)d_in[7];
    const float* b_f    = (const float*)d_in[8];
    const float* W1     = (const float*)d_in[9];
    const float* b1     = (const float*)d_in[10];
    const float* W2     = (const float*)d_in[11];
    const float* b2     = (const float*)d_in[12];
    float* out = (float*)d_out;

    // workspace: blockMod (1024 int) | perm (12672 int) | xbuf (4096*128 f32) | wf (split-bf16 weights)
    int* blockMod = (int*)d_ws;
    int* perm     = blockMod + 1024;
    float* xbuf   = (float*)(blockMod + 1024 + NSTEPS*NBMAX*TS);      // byte 54784 (16B aligned)
    unsigned short* wfb = (unsigned short*)(xbuf + (size_t)BB*EE);    // byte 2151936 (16B aligned)

    convert_kernel<<<NFRAGBLK, 256, 0, stream>>>(W_in, W_bias, W_f, W1, W2, wfb);
    prep_kernel<<<1, 1024, 0, stream>>>(module_ids, blockMod, perm);
    for (int t = 0; t < NSTEPS; t++) {
        step_kernel<<<NBMAX, 256, 0, stream>>>(t, entity_ids, embedding,
                                               b_in, b_bias, b_f,
                                               wfb, blockMod, perm, xbuf);
    }
    final_kernel<<<BB/TS, 256, 0, stream>>>(xbuf, b1, b2, wfb, out);
}

// Round 4
// 368.601 us; speedup vs baseline: 1.5083x; 1.0227x over previous
//
#include <hip/hip_runtime.h>

// Problem constants (from reference)
#define BB      4096
#define EE      128
#define MM      8
#define NSTEPS  3
#define HH      256
#define CC      16

#define TS      16                    // samples per block (MFMA M-tile)
#define NBMAX   (BB/TS + MM)          // 264: worst-case padded blocks per step
#define FB      1024                  // ushorts per weight frag-block (512 hi + 512 lo)

// frag-block ranges in wf:
//   W_in  : (m*8+nt)*4+kc            -> [0,256)
//   W_bias: 256 + (m*8+nt)*4+kc      -> [256,512)
//   W_f   : 512 + (m*8+nt)*8+kc      -> [512,1024)
//   W1    : 1024 + nt*4+kc (nt<16)   -> [1024,1088)
//   W2    : 1088 + kc      (kc<8)    -> [1088,1096)
#define NFRAGBLK 1096

// kernel-1 grid layout: [0,1096) wconvert | [1096,2120) econvert | [2120,2168) count
#define ECONV0   1096
#define COUNT0   2120
#define GRID1    2168

typedef __attribute__((ext_vector_type(8))) short  bf16x8;
typedef __attribute__((ext_vector_type(4))) float  f32x4;

__device__ __forceinline__ unsigned short bf16_rn(float v) {
    unsigned u = __float_as_uint(v);
    return (unsigned short)((u + 0x7FFFu + ((u >> 16) & 1u)) >> 16);
}
__device__ __forceinline__ float bf16_f(unsigned short h) {
    return __uint_as_float(((unsigned)h) << 16);
}
__device__ __forceinline__ void split8(const float* v, bf16x8& hi, bf16x8& lo) {
    #pragma unroll
    for (int i = 0; i < 8; i++) {
        unsigned short h = bf16_rn(v[i]);
        hi[i] = (short)h;
        lo[i] = (short)bf16_rn(v[i] - bf16_f(h));
    }
}
__device__ __forceinline__ void split1(float v, unsigned short& h, unsigned short& l) {
    h = bf16_rn(v);
    l = bf16_rn(v - bf16_f(h));
}
#define MFMA(a,b,c) __builtin_amdgcn_mfma_f32_16x16x32_bf16((a),(b),(c),0,0,0)
__device__ __forceinline__ f32x4 mfma3(bf16x8 ah, bf16x8 al, bf16x8 bh, bf16x8 bl, f32x4 c) {
    c = MFMA(ah, bh, c);
    c = MFMA(ah, bl, c);
    c = MFMA(al, bh, c);
    return c;
}

// ---------------------------------------------------------------------------
// kernel 1: weight convert (frag-linear split-bf16) | embedding gather-split | count
// ---------------------------------------------------------------------------
__global__ __launch_bounds__(256) void convert_kernel(
    const int*   __restrict__ entity_ids, const int* __restrict__ module_ids,
    const float* __restrict__ embedding,
    const float* __restrict__ W_in, const float* __restrict__ W_bias,
    const float* __restrict__ W_f,  const float* __restrict__ W1,
    const float* __restrict__ W2,
    unsigned short* __restrict__ wf,
    unsigned short* __restrict__ x0h, unsigned short* __restrict__ x0l,
    unsigned short* __restrict__ ebh, unsigned short* __restrict__ ebl,
    int* __restrict__ wcnt)
{
    const int b = blockIdx.x, tid = threadIdx.x;
    if (b < NFRAGBLK) {
        // ---- weight convert (B-fragment-linear, hi/lo split) ----
        unsigned short* dhi = wf + (size_t)b * FB;
        unsigned short* dlo = dhi + 512;
        #pragma unroll
        for (int half = 0; half < 2; half++) {
            const int el = tid + half * 256;
            const int ln = el >> 3, j = el & 7;
            const int krel = ((ln >> 4) << 3) + j;   // 0..31
            const int nrel = ln & 15;
            float v;
            if (b < 512) {
                const int bb = b & 255;
                const int kc = bb & 3, nt = (bb >> 2) & 7, m = bb >> 5;
                const float* src = (b < 256 ? W_in : W_bias) + (size_t)m * EE * EE;
                v = src[(size_t)(kc*32 + krel) * EE + nt*16 + nrel];
            } else if (b < 1024) {
                const int bb = b - 512;
                const int kc = bb & 7, nt = (bb >> 3) & 7, m = bb >> 6;
                v = W_f[(size_t)m * 2*EE*EE + (size_t)(kc*32 + krel) * EE + nt*16 + nrel];
            } else if (b < 1088) {
                const int bb = b - 1024;
                const int kc = bb & 3, nt = bb >> 2;
                v = W1[(size_t)(kc*32 + krel) * HH + nt*16 + nrel];
            } else {
                const int kc = b - 1088;
                v = W2[(size_t)(kc*32 + krel) * CC + nrel];
            }
            split1(v, dhi[el], dlo[el]);
        }
    } else if (b < COUNT0) {
        // ---- embedding gather + split: 16 rows per block ----
        const int u = b - ECONV0;
        const int g = u >> 8, wb = u & 255;       // g: 0=x0, 1..3=bias step g-1
        const int rloc = tid >> 4, cpart = tid & 15;
        const int s = wb*16 + rloc;
        const int eid = entity_ids[s*(NSTEPS+1) + g];   // g==0 -> col 0; else col t+1
        const float* src = embedding + (size_t)eid*EE + cpart*8;
        float vv[8];
        *(float4*)(vv)     = *(const float4*)(src);
        *(float4*)(vv + 4) = *(const float4*)(src + 4);
        bf16x8 hi, lo;
        split8(vv, hi, lo);
        unsigned short* dh = (g == 0 ? x0h : ebh + (size_t)(g-1)*BB*EE) + (size_t)s*EE + cpart*8;
        unsigned short* dl = (g == 0 ? x0l : ebl + (size_t)(g-1)*BB*EE) + (size_t)s*EE + cpart*8;
        *(bf16x8*)dh = hi;
        *(bf16x8*)dl = lo;
    } else {
        // ---- per-wave module histograms: block = (t, chunk of 256 samples) ----
        const int u = b - COUNT0;
        const int t = u >> 4, chunk = u & 15;
        const int wave = tid >> 6, lane = tid & 63;
        const int s = chunk*256 + wave*64 + lane;
        const int m = module_ids[s*NSTEPS + t];
        unsigned long long bal[MM];
        #pragma unroll
        for (int k = 0; k < MM; k++) bal[k] = __ballot(m == k);
        if (lane < MM)
            wcnt[((t*16 + chunk)*4 + wave)*MM + lane] = __popcll(bal[lane]);
    }
}

// ---------------------------------------------------------------------------
// kernel 2: plan — prefix-sum wave counts, bucket bases, blockMod, perm=-1
// ---------------------------------------------------------------------------
__global__ __launch_bounds__(256) void plan_kernel(
    const int* __restrict__ wcnt,
    int* __restrict__ blockMod,     // (NSTEPS, NBMAX)
    int* __restrict__ gbase,        // (NSTEPS,16,4,MM) absolute padded base per wave-slot
    int* __restrict__ perm)
{
    __shared__ int scnt[NSTEPS*16*4*MM];    // 1536
    __shared__ int tot [NSTEPS][MM];
    __shared__ int base[NSTEPS][MM];
    const int tid = threadIdx.x;

    for (int i = tid; i < NSTEPS*16*4*MM; i += 256) scnt[i] = wcnt[i];
    for (int i = tid; i < NSTEPS*NBMAX*TS; i += 256) perm[i] = -1;
    __syncthreads();

    if (tid < NSTEPS*MM) {          // totals per (t,m)
        const int t = tid / MM, m = tid % MM;
        int s = 0;
        for (int sl = 0; sl < 64; sl++) s += scnt[(t*64 + sl)*MM + m];
        tot[t][m] = s;
    }
    __syncthreads();
    if (tid < NSTEPS) {             // bucket bases + blockMod per step
        const int t = tid;
        int blk = 0;
        for (int m = 0; m < MM; m++) {
            base[t][m] = blk * TS;
            const int nb = (tot[t][m] + TS - 1) / TS;
            for (int b = 0; b < nb; b++) blockMod[t*NBMAX + blk + b] = m;
            blk += nb;
        }
        for (; blk < NBMAX; blk++) blockMod[t*NBMAX + blk] = -1;
    }
    __syncthreads();
    if (tid < NSTEPS*MM) {          // exclusive prefix -> absolute slot bases
        const int t = tid / MM, m = tid % MM;
        int run = base[t][m];
        for (int sl = 0; sl < 64; sl++) {
            const int idx = (t*64 + sl)*MM + m;
            gbase[idx] = run;
            run += scnt[idx];
        }
    }
}

// ---------------------------------------------------------------------------
// kernel 3: scatter — deterministic ballot-ranked bucket scatter
// ---------------------------------------------------------------------------
__global__ __launch_bounds__(256) void scatter_kernel(
    const int* __restrict__ module_ids,
    const int* __restrict__ gbase,
    int* __restrict__ perm)
{
    const int u = blockIdx.x;
    const int t = u >> 4, chunk = u & 15;
    const int tid = threadIdx.x, wave = tid >> 6, lane = tid & 63;
    __shared__ int gb[4*MM];
    if (tid < 4*MM) gb[tid] = gbase[((t*16 + chunk)*4)*MM + tid];
    __syncthreads();

    const int s = chunk*256 + wave*64 + lane;
    const int m = module_ids[s*NSTEPS + t];
    unsigned long long bal[MM];
    #pragma unroll
    for (int k = 0; k < MM; k++) bal[k] = __ballot(m == k);
    const unsigned long long below = (1ull << lane) - 1ull;
    const int rank = __popcll(bal[m] & below);
    perm[t*NBMAX*TS + gb[wave*MM + m] + rank] = s;
}

// ---------------------------------------------------------------------------
// kernel 4-6: one recurrent step. 512 thr = 8 waves, wave = n-tile.
// All operands pre-split bf16; h shared via frag-linear LDS (producer-split).
// ---------------------------------------------------------------------------
__global__ __launch_bounds__(512) void step_kernel(
    const int t,
    const unsigned short* __restrict__ x0h, const unsigned short* __restrict__ x0l,
    const unsigned short* __restrict__ ebh, const unsigned short* __restrict__ ebl,
    const float* __restrict__ b_in, const float* __restrict__ b_bias,
    const float* __restrict__ b_f,
    const unsigned short* __restrict__ wf,
    const int*   __restrict__ blockMod,
    const int*   __restrict__ perm,
    unsigned short* __restrict__ xsh, unsigned short* __restrict__ xsl)
{
    const int bid = blockIdx.x;
    const int m = blockMod[t*NBMAX + bid];
    if (m < 0) return;
    const int tid  = threadIdx.x;
    const int lane = tid & 63, wave = tid >> 6;          // wave = n-tile (0..7)
    const int row16 = lane & 15, quad = lane >> 4;
    const int pb = (t*NBMAX + bid)*TS;

    __shared__ __align__(16) unsigned short hfh[8][512]; // h, A-frag-linear, hi
    __shared__ __align__(16) unsigned short hfl[8][512]; // lo
    __shared__ int sids[TS];

    if (tid < TS) sids[tid] = perm[pb + tid];
    __syncthreads();

    const int sA  = sids[row16];
    const int sAc = sA < 0 ? 0 : sA;

    const unsigned short* xh_p = (t == 0 ? x0h : xsh) + (size_t)sAc*EE;
    const unsigned short* xl_p = (t == 0 ? x0l : xsl) + (size_t)sAc*EE;
    const unsigned short* eh_p = ebh + (size_t)t*BB*EE + (size_t)sAc*EE;
    const unsigned short* el_p = ebl + (size_t)t*BB*EE + (size_t)sAc*EE;

    bf16x8 xh[4], xl[4], eh[4], el_[4];
    #pragma unroll
    for (int kc = 0; kc < 4; kc++) {
        const int off = kc*32 + quad*8;
        xh[kc]  = *(const bf16x8*)(xh_p + off);
        xl[kc]  = *(const bf16x8*)(xl_p + off);
        eh[kc]  = *(const bf16x8*)(eh_p + off);
        el_[kc] = *(const bf16x8*)(el_p + off);
    }

    // phase 1: h_in, h_bi for this wave's 16 output cols
    f32x4 aci = {0.f,0.f,0.f,0.f}, acb = {0.f,0.f,0.f,0.f};
    #pragma unroll
    for (int kc = 0; kc < 4; kc++) {
        const unsigned short* bI = wf + (size_t)((m*8 + wave)*4 + kc)*FB;
        const unsigned short* bB = wf + (size_t)(256 + (m*8 + wave)*4 + kc)*FB;
        const bf16x8 wih = *(const bf16x8*)(bI + lane*8);
        const bf16x8 wil = *(const bf16x8*)(bI + 512 + lane*8);
        const bf16x8 wbh = *(const bf16x8*)(bB + lane*8);
        const bf16x8 wbl = *(const bf16x8*)(bB + 512 + lane*8);
        aci = mfma3(xh[kc], xl[kc], wih, wil, aci);
        acb = mfma3(eh[kc], el_[kc], wbh, wbl, acb);
    }

    // epilogue 1: relu+bias, producer-side split, frag-linear LDS store
    {
        const int col = wave*16 + row16;
        const float bin = b_in [m*EE + col];
        const float bbi = b_bias[m*EE + col];
        #pragma unroll
        for (int r = 0; r < 4; r++) {
            const int row = quad*4 + r;
            {   // h_in -> k = col
                const float v = fmaxf(aci[r] + bin, 0.f);
                const int k = col, kc = k >> 5;
                const int idx = (row + 16*((k >> 3) & 3))*8 + (k & 7);
                split1(v, hfh[kc][idx], hfl[kc][idx]);
            }
            {   // h_bi -> k = 128 + col
                const float v = fmaxf(acb[r] + bbi, 0.f);
                const int k = EE + col, kc = k >> 5;
                const int idx = (row + 16*((k >> 3) & 3))*8 + (k & 7);
                split1(v, hfh[kc][idx], hfl[kc][idx]);
            }
        }
    }
    __syncthreads();

    // phase 2: x_new = tanh(h W_f + b_f), K = 256
    f32x4 acf = {0.f,0.f,0.f,0.f};
    #pragma unroll
    for (int kc = 0; kc < 8; kc++) {
        const bf16x8 ah = *(const bf16x8*)(&hfh[kc][lane*8]);
        const bf16x8 al = *(const bf16x8*)(&hfl[kc][lane*8]);
        const unsigned short* bF = wf + (size_t)(512 + (m*8 + wave)*8 + kc)*FB;
        const bf16x8 wfh = *(const bf16x8*)(bF + lane*8);
        const bf16x8 wfl = *(const bf16x8*)(bF + 512 + lane*8);
        acf = mfma3(ah, al, wfh, wfl, acf);
    }
    {
        const int col = wave*16 + row16;
        const float bfv = b_f[m*EE + col];
        #pragma unroll
        for (int r = 0; r < 4; r++) {
            const int s = sids[quad*4 + r];
            if (s >= 0) {
                const float v = tanhf(acf[r] + bfv);
                unsigned short h, l;
                split1(v, h, l);
                xsh[(size_t)s*EE + col] = h;
                xsl[(size_t)s*EE + col] = l;
            }
        }
    }
}

// ---------------------------------------------------------------------------
// kernel 7: head. 256 blocks x 512 thr; W1 n-tiles 2/wave, W2 K-split + reduce.
// ---------------------------------------------------------------------------
__global__ __launch_bounds__(512) void final_kernel(
    const unsigned short* __restrict__ xsh, const unsigned short* __restrict__ xsl,
    const float* __restrict__ b1v, const float* __restrict__ b2,
    const unsigned short* __restrict__ wf,
    float* __restrict__ out)
{
    const int tid = threadIdx.x, bid = blockIdx.x;
    const int lane = tid & 63, wave = tid >> 6;
    const int row16 = lane & 15, quad = lane >> 4;
    const int sbase = bid * TS;

    __shared__ __align__(16) unsigned short hfh[8][512];
    __shared__ __align__(16) unsigned short hfl[8][512];
    __shared__ float red[8][TS][CC];

    const unsigned short* xh_p = xsh + (size_t)(sbase + row16)*EE;
    const unsigned short* xl_p = xsl + (size_t)(sbase + row16)*EE;
    bf16x8 xh[4], xl[4];
    #pragma unroll
    for (int kc = 0; kc < 4; kc++) {
        const int off = kc*32 + quad*8;
        xh[kc] = *(const bf16x8*)(xh_p + off);
        xl[kc] = *(const bf16x8*)(xl_p + off);
    }

    // h = relu(x W1 + b1): 16 n-tiles, 2 per wave
    f32x4 a1[2] = {{0.f,0.f,0.f,0.f},{0.f,0.f,0.f,0.f}};
    #pragma unroll
    for (int i = 0; i < 2; i++) {
        const int nt = wave + 8*i;
        #pragma unroll
        for (int kc = 0; kc < 4; kc++) {
            const unsigned short* bW = wf + (size_t)(1024 + nt*4 + kc)*FB;
            const bf16x8 wh = *(const bf16x8*)(bW + lane*8);
            const bf16x8 wl = *(const bf16x8*)(bW + 512 + lane*8);
            a1[i] = mfma3(xh[kc], xl[kc], wh, wl, a1[i]);
        }
    }
    #pragma unroll
    for (int i = 0; i < 2; i++) {
        const int col = (wave + 8*i)*16 + row16;     // 0..255
        const float b = b1v[col];
        #pragma unroll
        for (int r = 0; r < 4; r++) {
            const int row = quad*4 + r;
            const float v = fmaxf(a1[i][r] + b, 0.f);
            const int kc = col >> 5;
            const int idx = (row + 16*((col >> 3) & 3))*8 + (col & 7);
            split1(v, hfh[kc][idx], hfl[kc][idx]);
        }
    }
    __syncthreads();

    // out = h W2 + b2: K-split, wave = kc
    f32x4 a2 = {0.f,0.f,0.f,0.f};
    {
        const int kc = wave;
        const bf16x8 ah = *(const bf16x8*)(&hfh[kc][lane*8]);
        const bf16x8 al = *(const bf16x8*)(&hfl[kc][lane*8]);
        const unsigned short* bW = wf + (size_t)(1088 + kc)*FB;
        const bf16x8 wh = *(const bf16x8*)(bW + lane*8);
        const bf16x8 wl = *(const bf16x8*)(bW + 512 + lane*8);
        a2 = mfma3(ah, al, wh, wl, a2);
    }
    #pragma unroll
    for (int r = 0; r < 4; r++) red[wave][quad*4 + r][row16] = a2[r];
    __syncthreads();

    if (tid < TS*CC) {
        const int s = tid >> 4, c = tid & 15;
        float v = b2[c];
        #pragma unroll
        for (int w = 0; w < 8; w++) v += red[w][s][c];
        out[(size_t)(sbase + s)*CC + c] = v;
    }
}

// ---------------------------------------------------------------------------
extern "C" void kernel_launch(void* const* d_in, const int* in_sizes, int n_in,
                              void* d_out, int out_size, void* d_ws, size_t ws_size,
                              hipStream_t stream) {
    const int*   entity_ids = (const int*)  d_in[0];
    const int*   module_ids = (const int*)  d_in[1];
    const float* embedding  = (const float*)d_in[2];
    const float* W_in   = (const float*)d_in[3];
    const float* b_in   = (const float*)d_in[4];
    const float* W_bias = (const float*)d_in[5];
    const float* b_bias = (const float*)d_in[6];
    const float* W_f    = (const float*)d_in[7];
    const float* b_f    = (const float*)d_in[8];
    const float* W1     = (const float*)d_in[9];
    const float* b1     = (const float*)d_in[10];
    const float* W2     = (const float*)d_in[11];
    const float* b2     = (const float*)d_in[12];
    float* out = (float*)d_out;

    char* ws = (char*)d_ws;
    int* blockMod = (int*)(ws + 0);                       //  4 KB (792 used)
    int* perm     = (int*)(ws + 4096);                    //  50688 B
    int* wcnt     = (int*)(ws + 54784);                   //  6144 B
    int* gbase    = (int*)(ws + 60928);                   //  6144 B
    unsigned short* wfb = (unsigned short*)(ws + 131072);       // 2.25 MB
    unsigned short* x0h = (unsigned short*)(ws + (4u<<20));     // 1 MB each
    unsigned short* x0l = (unsigned short*)(ws + (5u<<20));
    unsigned short* xsh = (unsigned short*)(ws + (6u<<20));
    unsigned short* xsl = (unsigned short*)(ws + (7u<<20));
    unsigned short* ebh = (unsigned short*)(ws + (8u<<20));     // 3 MB (t-major)
    unsigned short* ebl = (unsigned short*)(ws + (11u<<20));    // 3 MB

    convert_kernel<<<GRID1, 256, 0, stream>>>(entity_ids, module_ids, embedding,
                                              W_in, W_bias, W_f, W1, W2,
                                              wfb, x0h, x0l, ebh, ebl, wcnt);
    plan_kernel<<<1, 256, 0, stream>>>(wcnt, blockMod, gbase, perm);
    scatter_kernel<<<48, 256, 0, stream>>>(module_ids, gbase, perm);
    for (int t = 0; t < NSTEPS; t++) {
        step_kernel<<<NBMAX, 512, 0, stream>>>(t, x0h, x0l, ebh, ebl,
                                               b_in, b_bias, b_f,
                                               wfb, blockMod, perm, xsh, xsl);
    }
    final_kernel<<<BB/TS, 512, 0, stream>>>(xsh, xsl, b1, b2, wfb, out);
}